// Round 4
// baseline (949.640 us; speedup 1.0000x reference)
//
#include <hip/hip_runtime.h>

typedef unsigned short u16;
typedef __attribute__((ext_vector_type(8))) short short8;   // 8 bf16
typedef __attribute__((ext_vector_type(4))) float f32x4;

// B=256, N=H=512, C=A=64, L=3, FC=256, FFC=32.  M := B*C = 16384 rows of xm.
// fp32 master state for residual/gates; bf16 shadows feed MFMA GEMMs.

__device__ __forceinline__ u16 f2b(float f) {
    union { float f; unsigned int i; } v; v.f = f;
    unsigned int x = v.i;
    x += 0x7fffu + ((x >> 16) & 1u);   // RNE
    return (u16)(x >> 16);
}

// ---------------- fp32 -> bf16 weight conversion
__global__ __launch_bounds__(256) void k_cvt(const float* __restrict__ src, u16* __restrict__ dst, int n4) {
    int i = blockIdx.x * 256 + threadIdx.x;
    if (i < n4) {
        float4 v = ((const float4*)src)[i];
        ushort4 o; o.x = f2b(v.x); o.y = f2b(v.y); o.z = f2b(v.z); o.w = f2b(v.w);
        ((ushort4*)dst)[i] = o;
    }
}

// ---------------- transpose: x[b,n,c] -> xm[(b*64+c)*512+n] fp32 + bf16
__global__ __launch_bounds__(256) void k_transpose(const float* __restrict__ x, float* __restrict__ xm,
                                                   u16* __restrict__ xmb) {
    __shared__ float tile[64][65];
    const int b  = blockIdx.y;
    const int n0 = blockIdx.x * 64;
    const int t  = threadIdx.x;
    const int c  = t & 63;
    const int dn = t >> 6;
#pragma unroll
    for (int i = 0; i < 16; ++i) {
        int nl = dn + i * 4;
        tile[c][nl] = x[((size_t)b * 512 + n0 + nl) * 64 + c];
    }
    __syncthreads();
    const int nl = t & 63;
    const int cb = (t >> 6) * 16;
#pragma unroll
    for (int i = 0; i < 16; ++i) {
        int c2 = cb + i;
        float v = tile[c2][nl];
        size_t idx = ((size_t)b * 64 + c2) * 512 + n0 + nl;
        xm[idx] = v;
        xmb[idx] = f2b(v);
    }
}

// ---------------- proj[b,a]
__global__ __launch_bounds__(64) void k_proj(const float* __restrict__ occ, const float* __restrict__ pw,
                                             const float* __restrict__ pb, float* __restrict__ proj) {
    const int b = blockIdx.x;
    const int a = threadIdx.x;
    const float* ob = occ + (size_t)b * 512;
    const float* wr = pw + (size_t)a * 512;
    float acc = 0.f;
    for (int n = 0; n < 512; ++n) acc += ob[n] * wr[n];
    proj[b * 64 + a] = acc + pb[a];
}

// ---------------- m1,m2 gate scalars per (b,c)
__global__ __launch_bounds__(64) void k_m(const float* __restrict__ xm,
                                          const float* __restrict__ g1w, const float* __restrict__ g1b,
                                          const float* __restrict__ g2w, const float* __restrict__ g2b,
                                          const float* __restrict__ proj, float* __restrict__ m1m2) {
    const int r = blockIdx.x;
    const int b = r >> 6, c = r & 63;
    const int lane = threadIdx.x;
    const float* row = xm + (size_t)r * 512;
    float a1 = 0.f, a2 = 0.f;
    for (int n = lane; n < 512; n += 64) {
        float xv = row[n];
        a1 += xv * g1w[n];
        a2 += xv * g2w[n];
    }
    a1 += proj[b * 64 + lane] * g1w[512 + lane];
    a2 += proj[b * 64 + c]    * g2w[512 + lane];
    for (int off = 32; off; off >>= 1) { a1 += __shfl_xor(a1, off); a2 += __shfl_xor(a2, off); }
    if (lane == 0) {
        float m1 = tanhf(a1 + g1b[0]); m1 = m1 > 0.f ? m1 : 0.f;
        float m2 = tanhf(a2 + g2b[0]); m2 = m2 > 0.f ? m2 : 0.f;
        m1m2[2 * r] = m1; m1m2[2 * r + 1] = m2;
    }
}

// ---------------- P-kernel (in-place vbuf -> P1,P2)
__global__ __launch_bounds__(64) void k_p(float* __restrict__ vb, const float* __restrict__ m1m2,
                                          const float* __restrict__ proj) {
    const int r = blockIdx.x;
    const int b = r >> 6, c = r & 63;
    const int a = threadIdx.x;
    const float m1 = m1m2[2 * r], m2 = m1m2[2 * r + 1];
    float s1 = m1 * vb[(size_t)r * 128 + a];       s1 = s1 > 0.f ? s1 : 0.f;
    float s2 = m2 * vb[(size_t)r * 128 + 64 + a];  s2 = s2 > 0.f ? s2 : 0.f;
    float mx1 = s1, mx2 = s2;
    for (int off = 32; off; off >>= 1) { mx1 = fmaxf(mx1, __shfl_xor(mx1, off)); mx2 = fmaxf(mx2, __shfl_xor(mx2, off)); }
    float e1 = expf(s1 - mx1), e2 = expf(s2 - mx2);
    float su1 = e1, su2 = e2;
    for (int off = 32; off; off >>= 1) { su1 += __shfl_xor(su1, off); su2 += __shfl_xor(su2, off); }
    vb[(size_t)r * 128 + a]      = proj[b * 64 + a] + e1 / su1;
    vb[(size_t)r * 128 + 64 + a] = proj[b * 64 + c] + e2 / su2;
}

// ---------------- adp -> transposed bf16: adpT[(b*64+v)*64 + c] = adp[c][v]
__global__ __launch_bounds__(256) void k_adp(const float* __restrict__ vb, u16* __restrict__ adpT) {
    __shared__ float P1s[64][64];
    __shared__ float P2s[64][65];
    __shared__ __align__(16) u16 Tl[64 * 72];
    const int b = blockIdx.x;
    const int t = threadIdx.x;
#pragma unroll
    for (int i = 0; i < 16; ++i) {
        int idx = t + 256 * i;
        int c = idx >> 6, a = idx & 63;
        P1s[c][a] = vb[((size_t)b * 64 + c) * 128 + a];
        P2s[c][a] = vb[((size_t)b * 64 + c) * 128 + 64 + a];
    }
    __syncthreads();
    const int lane = t & 63;   // v (softmax dim)
    const int w = t >> 6;
    for (int ci = 0; ci < 16; ++ci) {
        int c = w + ci * 4;
        float s = 0.f;
        for (int a = 0; a < 64; ++a) s += P1s[c][a] * P2s[lane][a];
        s = fmaxf(s, 0.f);
        float mx = s;
        for (int off = 32; off; off >>= 1) mx = fmaxf(mx, __shfl_xor(mx, off));
        float e = expf(s - mx);
        float su = e;
        for (int off = 32; off; off >>= 1) su += __shfl_xor(su, off);
        Tl[lane * 72 + c] = f2b(e / su);     // transposed: row v, col c
    }
    __syncthreads();
    const int v = t >> 2, ck = (t & 3) * 16;
    u16* dst = adpT + ((size_t)b * 64 + v) * 64 + ck;
    *(uint4*)dst       = *(const uint4*)&Tl[v * 72 + ck];
    *(uint4*)(dst + 8) = *(const uint4*)&Tl[v * 72 + ck + 8];
}

// ---------------- fused double nconv via MFMA: x1 = adp^T X, x2 = adp^T x1 (per b, n-tile 128)
__global__ __launch_bounds__(256) void k_nconv2(const u16* __restrict__ Xbf, const u16* __restrict__ adpT,
                                                u16* __restrict__ x1bf, u16* __restrict__ x2bf) {
    __shared__ __align__(16) u16 Ts[64 * 72];    // adpT rows v, cols c (k)
    __shared__ __align__(16) u16 Xs[128 * 72];   // XT rows n-local, cols c; reused for x1T
    const int b  = blockIdx.y;
    const int n0 = blockIdx.x * 128;
    const int t  = threadIdx.x;
    const int lane = t & 63, w = t >> 6;
    const int lrow = lane & 15, q = lane >> 4;
    const int wn = w * 32;

    { // stage adpT (already transposed, coalesced)
        int v = t >> 2, ck = (t & 3) * 8;
        const u16* src = adpT + ((size_t)b * 64 + v) * 64;
        *(uint4*)&Ts[v * 72 + ck]      = *(const uint4*)(src + ck);
        *(uint4*)&Ts[v * 72 + ck + 32] = *(const uint4*)(src + ck + 32);
    }
    { // stage X with in-LDS transpose: Xs[n][c]
        int c = t >> 2;
        const u16* xr = Xbf + ((size_t)b * 64 + c) * 512 + n0;
#pragma unroll
        for (int j = 0; j < 4; ++j) {
            int nn = j * 32 + (t & 3) * 8;
            uint4 vv = *(const uint4*)(xr + nn);
            const u16* pv = (const u16*)&vv;
#pragma unroll
            for (int e = 0; e < 8; ++e) Xs[(nn + e) * 72 + c] = pv[e];
        }
    }
    __syncthreads();

    const f32x4 zero = {0.f, 0.f, 0.f, 0.f};
    f32x4 acc[4][2];
#pragma unroll
    for (int mt = 0; mt < 4; ++mt)
#pragma unroll
        for (int nt = 0; nt < 2; ++nt) acc[mt][nt] = zero;

#pragma unroll
    for (int ks = 0; ks < 2; ++ks) {
        short8 af[4], bfr[2];
#pragma unroll
        for (int mt = 0; mt < 4; ++mt) af[mt]  = *(const short8*)&Ts[(mt * 16 + lrow) * 72 + ks * 32 + q * 8];
#pragma unroll
        for (int nt = 0; nt < 2; ++nt) bfr[nt] = *(const short8*)&Xs[(wn + nt * 16 + lrow) * 72 + ks * 32 + q * 8];
#pragma unroll
        for (int mt = 0; mt < 4; ++mt)
#pragma unroll
            for (int nt = 0; nt < 2; ++nt)
                acc[mt][nt] = __builtin_amdgcn_mfma_f32_16x16x32_bf16(af[mt], bfr[nt], acc[mt][nt], 0, 0, 0);
    }
    __syncthreads();   // all Xs reads done

    // write x1 -> global (32B segments) and x1^T -> Xs (for round 2)
#pragma unroll
    for (int mt = 0; mt < 4; ++mt)
#pragma unroll
        for (int nt = 0; nt < 2; ++nt) {
            int nl = wn + nt * 16 + lrow;
            ushort4 u;
            u.x = f2b(acc[mt][nt][0]); u.y = f2b(acc[mt][nt][1]);
            u.z = f2b(acc[mt][nt][2]); u.w = f2b(acc[mt][nt][3]);
            *(ushort4*)&Xs[nl * 72 + mt * 16 + q * 4] = u;
#pragma unroll
            for (int i = 0; i < 4; ++i)
                x1bf[((size_t)(b * 64 + mt * 16 + q * 4 + i)) * 512 + n0 + nl] = ((const u16*)&u)[i];
        }
    __syncthreads();

    f32x4 acc2[4][2];
#pragma unroll
    for (int mt = 0; mt < 4; ++mt)
#pragma unroll
        for (int nt = 0; nt < 2; ++nt) acc2[mt][nt] = zero;
#pragma unroll
    for (int ks = 0; ks < 2; ++ks) {
        short8 af[4], bfr[2];
#pragma unroll
        for (int mt = 0; mt < 4; ++mt) af[mt]  = *(const short8*)&Ts[(mt * 16 + lrow) * 72 + ks * 32 + q * 8];
#pragma unroll
        for (int nt = 0; nt < 2; ++nt) bfr[nt] = *(const short8*)&Xs[(wn + nt * 16 + lrow) * 72 + ks * 32 + q * 8];
#pragma unroll
        for (int mt = 0; mt < 4; ++mt)
#pragma unroll
            for (int nt = 0; nt < 2; ++nt)
                acc2[mt][nt] = __builtin_amdgcn_mfma_f32_16x16x32_bf16(af[mt], bfr[nt], acc2[mt][nt], 0, 0, 0);
    }
#pragma unroll
    for (int mt = 0; mt < 4; ++mt)
#pragma unroll
        for (int nt = 0; nt < 2; ++nt) {
            int nl = wn + nt * 16 + lrow;
#pragma unroll
            for (int i = 0; i < 4; ++i)
                x2bf[((size_t)(b * 64 + mt * 16 + q * 4 + i)) * 512 + n0 + nl] = f2b(acc2[mt][nt][i]);
        }
}

// ---------------- pipelined MFMA GEMM, BK=64, reg-prefetch double buffer
// out[m,n] = act(sum_k A[m,k]*W[n,k] + bias[n]) (+res). A segs stride 512, seg s covers k in [512s,512s+512).
template<int BM, int BN, int WM, int WN>
__global__ __launch_bounds__(256) void mfma_gemm(
    const u16* __restrict__ A0, const u16* __restrict__ A1, const u16* __restrict__ A2,
    const u16* __restrict__ W0, const u16* __restrict__ W1, int nsplit,
    const float* __restrict__ bias0, const float* __restrict__ bias1,
    const float* __restrict__ res, float* __restrict__ out, u16* __restrict__ outbf,
    int N, int K, int relu)
{
    constexpr int MT = BM / (16 * WM);
    constexpr int NT = BN / (16 * WN);
    constexpr int AP = BM / 64;
    constexpr int BP = BN / 64;
    __shared__ __align__(16) u16 SMEM[(BM + BN) * 72];
    u16* As = SMEM;
    u16* Bs = SMEM + BM * 72;
    const int t    = threadIdx.x;
    const int m0   = blockIdx.x * BM;
    const int n0   = blockIdx.y * BN;
    const int lane = t & 63;
    const int w    = t >> 6;
    const int wm   = (w / WN) * (16 * MT);
    const int wn   = (w % WN) * (16 * NT);
    const int lrow = lane & 15;
    const int q    = lane >> 4;
    const int srow = t >> 2;
    const int sk   = (t & 3) * 8;

    const u16* wrow[BP];
#pragma unroll
    for (int p = 0; p < BP; ++p) {
        int n = n0 + p * 64 + srow;
        wrow[p] = (n < nsplit) ? (W0 + (size_t)n * K) : (W1 + (size_t)(n - nsplit) * K);
    }

    uint4 ra[AP][2], rb[BP][2];
    auto loadTile = [&](int k0) {
        const u16* Abase = A0;
        int kloc = k0;
        if (k0 >= 512) { int seg = k0 >> 9; Abase = (seg == 1) ? A1 : A2; kloc = k0 & 511; }
#pragma unroll
        for (int p = 0; p < AP; ++p) {
            const u16* ar = Abase + (size_t)(m0 + p * 64 + srow) * 512 + kloc + sk;
            ra[p][0] = *(const uint4*)(ar);
            ra[p][1] = *(const uint4*)(ar + 32);
        }
#pragma unroll
        for (int p = 0; p < BP; ++p) {
            const u16* br = wrow[p] + k0 + sk;
            rb[p][0] = *(const uint4*)(br);
            rb[p][1] = *(const uint4*)(br + 32);
        }
    };
    auto storeTile = [&]() {
#pragma unroll
        for (int p = 0; p < AP; ++p) {
            *(uint4*)&As[(p * 64 + srow) * 72 + sk]      = ra[p][0];
            *(uint4*)&As[(p * 64 + srow) * 72 + sk + 32] = ra[p][1];
        }
#pragma unroll
        for (int p = 0; p < BP; ++p) {
            *(uint4*)&Bs[(p * 64 + srow) * 72 + sk]      = rb[p][0];
            *(uint4*)&Bs[(p * 64 + srow) * 72 + sk + 32] = rb[p][1];
        }
    };

    const f32x4 zero = {0.f, 0.f, 0.f, 0.f};
    f32x4 acc[MT][NT];
#pragma unroll
    for (int i = 0; i < MT; ++i)
#pragma unroll
        for (int j = 0; j < NT; ++j) acc[i][j] = zero;

    loadTile(0);
    storeTile();
    const int iters = K >> 6;
    for (int it = 0; it < iters; ++it) {
        __syncthreads();                       // staged tile visible
        if (it + 1 < iters) loadTile((it + 1) * 64);   // prefetch next (latency hidden under MFMA)
#pragma unroll
        for (int ks = 0; ks < 2; ++ks) {
            short8 af[MT], bfr[NT];
#pragma unroll
            for (int mt = 0; mt < MT; ++mt)
                af[mt] = *(const short8*)&As[(wm + mt * 16 + lrow) * 72 + ks * 32 + q * 8];
#pragma unroll
            for (int nt = 0; nt < NT; ++nt)
                bfr[nt] = *(const short8*)&Bs[(wn + nt * 16 + lrow) * 72 + ks * 32 + q * 8];
#pragma unroll
            for (int mt = 0; mt < MT; ++mt)
#pragma unroll
                for (int nt = 0; nt < NT; ++nt)
                    acc[mt][nt] = __builtin_amdgcn_mfma_f32_16x16x32_bf16(af[mt], bfr[nt], acc[mt][nt], 0, 0, 0);
        }
        if (it + 1 < iters) {
            __syncthreads();                   // all frag reads done
            storeTile();                       // waits vmcnt via compiler, overwrites LDS
        }
    }

    __syncthreads();                           // safe to reuse SMEM as repack buffer
    constexpr int RS = BN + 8;
    u16* rep = SMEM;
#pragma unroll
    for (int mt = 0; mt < MT; ++mt) {
        int mb = wm + mt * 16 + q * 4;
#pragma unroll
        for (int nt = 0; nt < NT; ++nt) {
            int nl = wn + nt * 16 + lrow;
            int n = n0 + nl;
            float bv = (n < nsplit) ? bias0[n] : bias1[n - nsplit];
#pragma unroll
            for (int i = 0; i < 4; ++i) {
                float v = acc[mt][nt][i] + bv;
                if (relu) v = fmaxf(v, 0.f);
                if (res) v += res[(size_t)(m0 + mb + i) * N + n];
                if (out) out[(size_t)(m0 + mb + i) * N + n] = v;
                if (outbf) rep[(mb + i) * RS + nl] = f2b(v);
            }
        }
    }
    if (outbf) {
        __syncthreads();
        for (int e = t; e < BM * (BN / 8); e += 256) {
            int row = e / (BN / 8);
            int ch  = e % (BN / 8);
            *(uint4*)(outbf + (size_t)(m0 + row) * N + n0 + ch * 8) = *(const uint4*)&rep[row * RS + ch * 8];
        }
    }
}

// ---------------- dvec[r] = t[r,:256] . d2_w + d2_b
__global__ __launch_bounds__(256) void k_dvec(const float* __restrict__ tmat, const float* __restrict__ d2w,
                                              const float* __restrict__ d2b, float* __restrict__ dvec) {
    const int r = blockIdx.x * 4 + (threadIdx.x >> 6);
    const int lane = threadIdx.x & 63;
    const float* row = tmat + (size_t)r * 256;
    float acc = 0.f;
    for (int f = lane; f < 256; f += 64) acc += row[f] * d2w[f];
    for (int off = 32; off; off >>= 1) acc += __shfl_xor(acc, off);
    if (lane == 0) dvec[r] = acc + d2b[0];
}

// ---------------- channel decoder + abs
__global__ __launch_bounds__(64) void k_final(const float* __restrict__ dvec, const float* __restrict__ c1w,
                                              const float* __restrict__ c1b, const float* __restrict__ c2w,
                                              const float* __restrict__ c2b, float* __restrict__ out) {
    const int b = blockIdx.x;
    const int f = threadIdx.x;
    float part = 0.f;
    if (f < 32) {
        float acc = c1b[f];
        const float* dr = dvec + b * 64;
        for (int c = 0; c < 64; ++c) acc += dr[c] * c1w[f * 64 + c];
        acc = acc > 0.f ? acc : 0.f;
        part = acc * c2w[f];
    }
    for (int off = 32; off; off >>= 1) part += __shfl_xor(part, off);
    if (f == 0) out[b] = fabsf(part + c2b[0]);
}

extern "C" void kernel_launch(void* const* d_in, const int* in_sizes, int n_in,
                              void* d_out, int out_size, void* d_ws, size_t ws_size,
                              hipStream_t stream) {
    const float* x     = (const float*)d_in[0];
    const float* occ   = (const float*)d_in[1];
    const float* projw = (const float*)d_in[2];
    const float* projb = (const float*)d_in[3];
    const float* ll1w  = (const float*)d_in[4];
    const float* ll1b  = (const float*)d_in[5];
    const float* ll2w  = (const float*)d_in[6];
    const float* ll2b  = (const float*)d_in[7];
    const float* g1w   = (const float*)d_in[8];
    const float* g1b   = (const float*)d_in[9];
    const float* g2w   = (const float*)d_in[10];
    const float* g2b   = (const float*)d_in[11];
    const float* gcw   = (const float*)d_in[12];
    const float* gcb   = (const float*)d_in[13];
    const float* taw   = (const float*)d_in[14];
    const float* tab   = (const float*)d_in[15];
    const float* d1w   = (const float*)d_in[16];
    const float* d1b   = (const float*)d_in[17];
    const float* d2w   = (const float*)d_in[18];
    const float* d2b   = (const float*)d_in[19];
    const float* c1w   = (const float*)d_in[20];
    const float* c1b   = (const float*)d_in[21];
    const float* c2w   = (const float*)d_in[22];
    const float* c2b   = (const float*)d_in[23];

    const size_t MR = (size_t)16384 * 512;
    float* ws   = (float*)d_ws;
    float* xmA  = ws;                         // fp32 state A
    float* xmB  = xmA + MR;                   // fp32 state B
    float* x2T  = xmB + MR;                   // d1 output (fp32)
    float* vbuf = x2T + MR;                   // 16384*128
    float* proj = vbuf + (size_t)16384 * 128;
    float* m1m2 = proj + 16384;
    float* dvec = m1m2 + 32768;
    u16* bfb     = (u16*)(dvec + 16384);
    u16* xmA_bf  = bfb;
    u16* xmB_bf  = xmA_bf + MR;
    u16* x1_bf   = xmB_bf + MR;
    u16* x2_bf   = x1_bf + MR;
    u16* x1T_bf  = x2_bf + MR;                // ta output (bf16 only)
    u16* adpT_bf = x1T_bf + MR;               // 16384*64
    u16* ll1w_bf = adpT_bf + (size_t)16384 * 64;
    u16* ll2w_bf = ll1w_bf + 98304;
    u16* gcw_bf  = ll2w_bf + 98304;           // 3*512*1536
    u16* taw_bf  = gcw_bf + 2359296;
    u16* d1w_bf  = taw_bf + 262144;

    k_cvt<<<96,   256, 0, stream>>>(ll1w, ll1w_bf, 98304 / 4);
    k_cvt<<<96,   256, 0, stream>>>(ll2w, ll2w_bf, 98304 / 4);
    k_cvt<<<2304, 256, 0, stream>>>(gcw,  gcw_bf,  2359296 / 4);
    k_cvt<<<256,  256, 0, stream>>>(taw,  taw_bf,  262144 / 4);
    k_cvt<<<128,  256, 0, stream>>>(d1w,  d1w_bf,  131072 / 4);

    k_transpose<<<dim3(8, 256), 256, 0, stream>>>(x, xmA, xmA_bf);
    k_proj<<<256, 64, 0, stream>>>(occ, projw, projb, proj);

    float* cur = xmA;  u16* cur_bf = xmA_bf;
    float* nxt = xmB;  u16* nxt_bf = xmB_bf;
    for (int l = 0; l < 3; ++l) {
        k_m<<<16384, 64, 0, stream>>>(cur, g1w + l * 576, g1b + l, g2w + l * 576, g2b + l, proj, m1m2);
        mfma_gemm<64, 64, 1, 4><<<dim3(256, 2), 256, 0, stream>>>(
            cur_bf, nullptr, nullptr,
            ll1w_bf + (size_t)l * 32768, ll2w_bf + (size_t)l * 32768, 64,
            ll1b + l * 64, ll2b + l * 64, nullptr, vbuf, nullptr, 128, 512, 0);
        k_p<<<16384, 64, 0, stream>>>(vbuf, m1m2, proj);
        k_adp<<<256, 256, 0, stream>>>(vbuf, adpT_bf);
        k_nconv2<<<dim3(4, 256), 256, 0, stream>>>(cur_bf, adpT_bf, x1_bf, x2_bf);
        mfma_gemm<128, 128, 2, 2><<<dim3(128, 4), 256, 0, stream>>>(
            cur_bf, x1_bf, x2_bf,
            gcw_bf + (size_t)l * 786432, gcw_bf + (size_t)l * 786432, 512,
            gcb + l * 512, gcb + l * 512, (l > 0 ? cur : nullptr), nxt, nxt_bf, 512, 1536, 1);
        { float* tf = cur; cur = nxt; nxt = tf; }
        { u16* tb = cur_bf; cur_bf = nxt_bf; nxt_bf = tb; }
    }
    // temporal_agg: bf16-only output (nothing reads it in fp32)
    mfma_gemm<128, 128, 2, 2><<<dim3(128, 4), 256, 0, stream>>>(
        cur_bf, nullptr, nullptr, taw_bf, taw_bf, 512, tab, tab, nullptr, nullptr, x1T_bf, 512, 512, 0);
    // decoder1: fp32 output
    mfma_gemm<128, 128, 2, 2><<<dim3(128, 2), 256, 0, stream>>>(
        x1T_bf, nullptr, nullptr, d1w_bf, d1w_bf, 256, d1b, d1b, nullptr, x2T, nullptr, 256, 512, 1);
    k_dvec<<<4096, 256, 0, stream>>>(x2T, d2w, d2b, dvec);
    k_final<<<256, 64, 0, stream>>>(dvec, c1w, c1b, c2w, c2b, (float*)d_out);
}

// Round 5
// 545.009 us; speedup vs baseline: 1.7424x; 1.7424x over previous
//
#include <hip/hip_runtime.h>

typedef unsigned short u16;
typedef __attribute__((ext_vector_type(8))) short short8;   // 8 bf16
typedef __attribute__((ext_vector_type(4))) float f32x4;

// B=256, N=H=512, C=A=64, L=3, FC=256, FFC=32.  M := B*C = 16384 rows of xm.
// fp32 master state for residual/gates; bf16 shadows feed MFMA GEMMs.

__device__ __forceinline__ u16 f2b(float f) {
    union { float f; unsigned int i; } v; v.f = f;
    unsigned int x = v.i;
    x += 0x7fffu + ((x >> 16) & 1u);   // RNE
    return (u16)(x >> 16);
}

// ---------------- fp32 -> bf16 weight conversion
__global__ __launch_bounds__(256) void k_cvt(const float* __restrict__ src, u16* __restrict__ dst, int n4) {
    int i = blockIdx.x * 256 + threadIdx.x;
    if (i < n4) {
        float4 v = ((const float4*)src)[i];
        ushort4 o; o.x = f2b(v.x); o.y = f2b(v.y); o.z = f2b(v.z); o.w = f2b(v.w);
        ((ushort4*)dst)[i] = o;
    }
}

// ---------------- transpose: x[b,n,c] -> xm[(b*64+c)*512+n] fp32 + bf16
__global__ __launch_bounds__(256) void k_transpose(const float* __restrict__ x, float* __restrict__ xm,
                                                   u16* __restrict__ xmb) {
    __shared__ float tile[64][65];
    const int b  = blockIdx.y;
    const int n0 = blockIdx.x * 64;
    const int t  = threadIdx.x;
    const int c  = t & 63;
    const int dn = t >> 6;
#pragma unroll
    for (int i = 0; i < 16; ++i) {
        int nl = dn + i * 4;
        tile[c][nl] = x[((size_t)b * 512 + n0 + nl) * 64 + c];
    }
    __syncthreads();
    const int nl = t & 63;
    const int cb = (t >> 6) * 16;
#pragma unroll
    for (int i = 0; i < 16; ++i) {
        int c2 = cb + i;
        float v = tile[c2][nl];
        size_t idx = ((size_t)b * 64 + c2) * 512 + n0 + nl;
        xm[idx] = v;
        xmb[idx] = f2b(v);
    }
}

// ---------------- proj[b,a]
__global__ __launch_bounds__(64) void k_proj(const float* __restrict__ occ, const float* __restrict__ pw,
                                             const float* __restrict__ pb, float* __restrict__ proj) {
    const int b = blockIdx.x;
    const int a = threadIdx.x;
    const float* ob = occ + (size_t)b * 512;
    const float* wr = pw + (size_t)a * 512;
    float acc = 0.f;
    for (int n = 0; n < 512; ++n) acc += ob[n] * wr[n];
    proj[b * 64 + a] = acc + pb[a];
}

// ---------------- m1,m2 gate scalars per (b,c)
__global__ __launch_bounds__(64) void k_m(const float* __restrict__ xm,
                                          const float* __restrict__ g1w, const float* __restrict__ g1b,
                                          const float* __restrict__ g2w, const float* __restrict__ g2b,
                                          const float* __restrict__ proj, float* __restrict__ m1m2) {
    const int r = blockIdx.x;
    const int b = r >> 6, c = r & 63;
    const int lane = threadIdx.x;
    const float* row = xm + (size_t)r * 512;
    float a1 = 0.f, a2 = 0.f;
    for (int n = lane; n < 512; n += 64) {
        float xv = row[n];
        a1 += xv * g1w[n];
        a2 += xv * g2w[n];
    }
    a1 += proj[b * 64 + lane] * g1w[512 + lane];
    a2 += proj[b * 64 + c]    * g2w[512 + lane];
    for (int off = 32; off; off >>= 1) { a1 += __shfl_xor(a1, off); a2 += __shfl_xor(a2, off); }
    if (lane == 0) {
        float m1 = tanhf(a1 + g1b[0]); m1 = m1 > 0.f ? m1 : 0.f;
        float m2 = tanhf(a2 + g2b[0]); m2 = m2 > 0.f ? m2 : 0.f;
        m1m2[2 * r] = m1; m1m2[2 * r + 1] = m2;
    }
}

// ---------------- P-kernel (in-place vbuf -> P1,P2)
__global__ __launch_bounds__(64) void k_p(float* __restrict__ vb, const float* __restrict__ m1m2,
                                          const float* __restrict__ proj) {
    const int r = blockIdx.x;
    const int b = r >> 6, c = r & 63;
    const int a = threadIdx.x;
    const float m1 = m1m2[2 * r], m2 = m1m2[2 * r + 1];
    float s1 = m1 * vb[(size_t)r * 128 + a];       s1 = s1 > 0.f ? s1 : 0.f;
    float s2 = m2 * vb[(size_t)r * 128 + 64 + a];  s2 = s2 > 0.f ? s2 : 0.f;
    float mx1 = s1, mx2 = s2;
    for (int off = 32; off; off >>= 1) { mx1 = fmaxf(mx1, __shfl_xor(mx1, off)); mx2 = fmaxf(mx2, __shfl_xor(mx2, off)); }
    float e1 = expf(s1 - mx1), e2 = expf(s2 - mx2);
    float su1 = e1, su2 = e2;
    for (int off = 32; off; off >>= 1) { su1 += __shfl_xor(su1, off); su2 += __shfl_xor(su2, off); }
    vb[(size_t)r * 128 + a]      = proj[b * 64 + a] + e1 / su1;
    vb[(size_t)r * 128 + 64 + a] = proj[b * 64 + c] + e2 / su2;
}

// ---------------- adp -> transposed bf16: adpT[(b*64+v)*64 + c] = adp[c][v]
__global__ __launch_bounds__(256) void k_adp(const float* __restrict__ vb, u16* __restrict__ adpT) {
    __shared__ float P1s[64][64];
    __shared__ float P2s[64][65];
    __shared__ __align__(16) u16 Tl[64 * 72];
    const int b = blockIdx.x;
    const int t = threadIdx.x;
#pragma unroll
    for (int i = 0; i < 16; ++i) {
        int idx = t + 256 * i;
        int c = idx >> 6, a = idx & 63;
        P1s[c][a] = vb[((size_t)b * 64 + c) * 128 + a];
        P2s[c][a] = vb[((size_t)b * 64 + c) * 128 + 64 + a];
    }
    __syncthreads();
    const int lane = t & 63;   // v (softmax dim)
    const int w = t >> 6;
    for (int ci = 0; ci < 16; ++ci) {
        int c = w + ci * 4;
        float s = 0.f;
        for (int a = 0; a < 64; ++a) s += P1s[c][a] * P2s[lane][a];
        s = fmaxf(s, 0.f);
        float mx = s;
        for (int off = 32; off; off >>= 1) mx = fmaxf(mx, __shfl_xor(mx, off));
        float e = expf(s - mx);
        float su = e;
        for (int off = 32; off; off >>= 1) su += __shfl_xor(su, off);
        Tl[lane * 72 + c] = f2b(e / su);     // transposed: row v, col c
    }
    __syncthreads();
    const int v = t >> 2, ck = (t & 3) * 16;
    u16* dst = adpT + ((size_t)b * 64 + v) * 64 + ck;
    *(uint4*)dst       = *(const uint4*)&Tl[v * 72 + ck];
    *(uint4*)(dst + 8) = *(const uint4*)&Tl[v * 72 + ck + 8];
}

// ---------------- fused double nconv via MFMA: x1 = adp^T X, x2 = adp^T x1 (per b, n-tile 128)
__global__ __launch_bounds__(256) void k_nconv2(const u16* __restrict__ Xbf, const u16* __restrict__ adpT,
                                                u16* __restrict__ x1bf, u16* __restrict__ x2bf) {
    __shared__ __align__(16) u16 Ts[64 * 72];    // adpT rows v, cols c (k)
    __shared__ __align__(16) u16 Xs[128 * 72];   // XT rows n-local, cols c; reused for x1T
    const int b  = blockIdx.y;
    const int n0 = blockIdx.x * 128;
    const int t  = threadIdx.x;
    const int lane = t & 63, w = t >> 6;
    const int lrow = lane & 15, q = lane >> 4;
    const int wn = w * 32;

    { // stage adpT (already transposed, coalesced)
        int v = t >> 2, ck = (t & 3) * 8;
        const u16* src = adpT + ((size_t)b * 64 + v) * 64;
        *(uint4*)&Ts[v * 72 + ck]      = *(const uint4*)(src + ck);
        *(uint4*)&Ts[v * 72 + ck + 32] = *(const uint4*)(src + ck + 32);
    }
    { // stage X with in-LDS transpose: Xs[n][c]
        int c = t >> 2;
        const u16* xr = Xbf + ((size_t)b * 64 + c) * 512 + n0;
#pragma unroll
        for (int j = 0; j < 4; ++j) {
            int nn = j * 32 + (t & 3) * 8;
            uint4 vv = *(const uint4*)(xr + nn);
            const u16* pv = (const u16*)&vv;
#pragma unroll
            for (int e = 0; e < 8; ++e) Xs[(nn + e) * 72 + c] = pv[e];
        }
    }
    __syncthreads();

    const f32x4 zero = {0.f, 0.f, 0.f, 0.f};
    f32x4 acc[4][2];
#pragma unroll
    for (int mt = 0; mt < 4; ++mt)
#pragma unroll
        for (int nt = 0; nt < 2; ++nt) acc[mt][nt] = zero;

#pragma unroll
    for (int ks = 0; ks < 2; ++ks) {
        short8 af[4], bfr[2];
#pragma unroll
        for (int mt = 0; mt < 4; ++mt) af[mt]  = *(const short8*)&Ts[(mt * 16 + lrow) * 72 + ks * 32 + q * 8];
#pragma unroll
        for (int nt = 0; nt < 2; ++nt) bfr[nt] = *(const short8*)&Xs[(wn + nt * 16 + lrow) * 72 + ks * 32 + q * 8];
#pragma unroll
        for (int mt = 0; mt < 4; ++mt)
#pragma unroll
            for (int nt = 0; nt < 2; ++nt)
                acc[mt][nt] = __builtin_amdgcn_mfma_f32_16x16x32_bf16(af[mt], bfr[nt], acc[mt][nt], 0, 0, 0);
    }
    __syncthreads();   // all Xs reads done

    // write x1 -> global and x1^T -> Xs (for round 2)
#pragma unroll
    for (int mt = 0; mt < 4; ++mt)
#pragma unroll
        for (int nt = 0; nt < 2; ++nt) {
            int nl = wn + nt * 16 + lrow;
            ushort4 u;
            u.x = f2b(acc[mt][nt][0]); u.y = f2b(acc[mt][nt][1]);
            u.z = f2b(acc[mt][nt][2]); u.w = f2b(acc[mt][nt][3]);
            *(ushort4*)&Xs[nl * 72 + mt * 16 + q * 4] = u;
#pragma unroll
            for (int i = 0; i < 4; ++i)
                x1bf[((size_t)(b * 64 + mt * 16 + q * 4 + i)) * 512 + n0 + nl] = ((const u16*)&u)[i];
        }
    __syncthreads();

    f32x4 acc2[4][2];
#pragma unroll
    for (int mt = 0; mt < 4; ++mt)
#pragma unroll
        for (int nt = 0; nt < 2; ++nt) acc2[mt][nt] = zero;
#pragma unroll
    for (int ks = 0; ks < 2; ++ks) {
        short8 af[4], bfr[2];
#pragma unroll
        for (int mt = 0; mt < 4; ++mt) af[mt]  = *(const short8*)&Ts[(mt * 16 + lrow) * 72 + ks * 32 + q * 8];
#pragma unroll
        for (int nt = 0; nt < 2; ++nt) bfr[nt] = *(const short8*)&Xs[(wn + nt * 16 + lrow) * 72 + ks * 32 + q * 8];
#pragma unroll
        for (int mt = 0; mt < 4; ++mt)
#pragma unroll
            for (int nt = 0; nt < 2; ++nt)
                acc2[mt][nt] = __builtin_amdgcn_mfma_f32_16x16x32_bf16(af[mt], bfr[nt], acc2[mt][nt], 0, 0, 0);
    }
#pragma unroll
    for (int mt = 0; mt < 4; ++mt)
#pragma unroll
        for (int nt = 0; nt < 2; ++nt) {
            int nl = wn + nt * 16 + lrow;
#pragma unroll
            for (int i = 0; i < 4; ++i)
                x2bf[((size_t)(b * 64 + mt * 16 + q * 4 + i)) * 512 + n0 + nl] = f2b(acc2[mt][nt][i]);
        }
}

// ---------------- MFMA GEMM (R3 structure): BK=32, load->LDS->sync->compute->sync.
// out[m,n] = act(sum_k A[m,k]*W[n,k] + bias[n]) (+res). A segs stride 512, seg s covers k in [512s,512s+512).
// 4 waves as 2x2; wave tile (BM/2, BN/2); MT=BM/32, NT=BN/32.
template<int BM, int BN>
__global__ __launch_bounds__(256) void mfma_gemm(
    const u16* __restrict__ A0, const u16* __restrict__ A1, const u16* __restrict__ A2,
    const u16* __restrict__ W0, const u16* __restrict__ W1, int nsplit,
    const float* __restrict__ bias0, const float* __restrict__ bias1,
    const float* __restrict__ res, float* __restrict__ out, u16* __restrict__ outbf,
    int N, int K, int relu)
{
    constexpr int MT = BM / 32;
    constexpr int NT = BN / 32;
    constexpr int AP = BM / 64;
    constexpr int BP = BN / 64;
    __shared__ __align__(16) u16 As[BM * 40];   // +8 shorts pad per row
    __shared__ __align__(16) u16 Bs[BN * 40];
    const int t    = threadIdx.x;
    const int m0   = blockIdx.x * BM;
    const int n0   = blockIdx.y * BN;
    const int lane = t & 63;
    const int w    = t >> 6;
    const int wm   = (w >> 1) * (BM / 2);
    const int wn   = (w & 1) * (BN / 2);
    const int lrow = lane & 15;
    const int q    = lane >> 4;
    const int srow = t >> 2;      // 0..63
    const int skq  = t & 3;       // 16B chunk within 64B k-row

    const f32x4 zero = {0.f, 0.f, 0.f, 0.f};
    f32x4 acc[MT][NT];
#pragma unroll
    for (int i = 0; i < MT; ++i)
#pragma unroll
        for (int j = 0; j < NT; ++j) acc[i][j] = zero;

    for (int k0 = 0; k0 < K; k0 += 32) {
        const u16* Abase = A0;
        int kloc = k0;
        if (K > 512) {
            int seg = k0 >> 9;
            Abase = (seg == 0) ? A0 : ((seg == 1) ? A1 : A2);
            kloc = k0 & 511;
        }
        uint4 av[AP], bv[BP];
#pragma unroll
        for (int p = 0; p < AP; ++p)
            av[p] = *(const uint4*)(Abase + (size_t)(m0 + p * 64 + srow) * 512 + kloc + skq * 8);
#pragma unroll
        for (int p = 0; p < BP; ++p) {
            int n = n0 + p * 64 + srow;
            const u16* wr = (n < nsplit) ? (W0 + (size_t)n * K) : (W1 + (size_t)(n - nsplit) * K);
            bv[p] = *(const uint4*)(wr + k0 + skq * 8);
        }
#pragma unroll
        for (int p = 0; p < AP; ++p) *(uint4*)&As[(p * 64 + srow) * 40 + skq * 8] = av[p];
#pragma unroll
        for (int p = 0; p < BP; ++p) *(uint4*)&Bs[(p * 64 + srow) * 40 + skq * 8] = bv[p];
        __syncthreads();

        short8 af[MT], bfr[NT];
#pragma unroll
        for (int mt = 0; mt < MT; ++mt)
            af[mt] = *(const short8*)&As[(wm + mt * 16 + lrow) * 40 + q * 8];
#pragma unroll
        for (int nt = 0; nt < NT; ++nt)
            bfr[nt] = *(const short8*)&Bs[(wn + nt * 16 + lrow) * 40 + q * 8];
#pragma unroll
        for (int mt = 0; mt < MT; ++mt)
#pragma unroll
            for (int nt = 0; nt < NT; ++nt)
                acc[mt][nt] = __builtin_amdgcn_mfma_f32_16x16x32_bf16(af[mt], bfr[nt], acc[mt][nt], 0, 0, 0);
        __syncthreads();
    }

#pragma unroll
    for (int mt = 0; mt < MT; ++mt) {
        int mb = m0 + wm + mt * 16 + q * 4;
#pragma unroll
        for (int nt = 0; nt < NT; ++nt) {
            int n = n0 + wn + nt * 16 + lrow;
            float bvv = (n < nsplit) ? bias0[n] : bias1[n - nsplit];
#pragma unroll
            for (int i = 0; i < 4; ++i) {
                float v = acc[mt][nt][i] + bvv;
                if (relu) v = fmaxf(v, 0.f);
                if (res) v += res[(size_t)(mb + i) * N + n];
                if (out) out[(size_t)(mb + i) * N + n] = v;
                if (outbf) outbf[(size_t)(mb + i) * N + n] = f2b(v);
            }
        }
    }
}

// ---------------- dvec[r] = t[r,:256] . d2_w + d2_b
__global__ __launch_bounds__(256) void k_dvec(const float* __restrict__ tmat, const float* __restrict__ d2w,
                                              const float* __restrict__ d2b, float* __restrict__ dvec) {
    const int r = blockIdx.x * 4 + (threadIdx.x >> 6);
    const int lane = threadIdx.x & 63;
    const float* row = tmat + (size_t)r * 256;
    float acc = 0.f;
    for (int f = lane; f < 256; f += 64) acc += row[f] * d2w[f];
    for (int off = 32; off; off >>= 1) acc += __shfl_xor(acc, off);
    if (lane == 0) dvec[r] = acc + d2b[0];
}

// ---------------- channel decoder + abs
__global__ __launch_bounds__(64) void k_final(const float* __restrict__ dvec, const float* __restrict__ c1w,
                                              const float* __restrict__ c1b, const float* __restrict__ c2w,
                                              const float* __restrict__ c2b, float* __restrict__ out) {
    const int b = blockIdx.x;
    const int f = threadIdx.x;
    float part = 0.f;
    if (f < 32) {
        float acc = c1b[f];
        const float* dr = dvec + b * 64;
        for (int c = 0; c < 64; ++c) acc += dr[c] * c1w[f * 64 + c];
        acc = acc > 0.f ? acc : 0.f;
        part = acc * c2w[f];
    }
    for (int off = 32; off; off >>= 1) part += __shfl_xor(part, off);
    if (f == 0) out[b] = fabsf(part + c2b[0]);
}

extern "C" void kernel_launch(void* const* d_in, const int* in_sizes, int n_in,
                              void* d_out, int out_size, void* d_ws, size_t ws_size,
                              hipStream_t stream) {
    const float* x     = (const float*)d_in[0];
    const float* occ   = (const float*)d_in[1];
    const float* projw = (const float*)d_in[2];
    const float* projb = (const float*)d_in[3];
    const float* ll1w  = (const float*)d_in[4];
    const float* ll1b  = (const float*)d_in[5];
    const float* ll2w  = (const float*)d_in[6];
    const float* ll2b  = (const float*)d_in[7];
    const float* g1w   = (const float*)d_in[8];
    const float* g1b   = (const float*)d_in[9];
    const float* g2w   = (const float*)d_in[10];
    const float* g2b   = (const float*)d_in[11];
    const float* gcw   = (const float*)d_in[12];
    const float* gcb   = (const float*)d_in[13];
    const float* taw   = (const float*)d_in[14];
    const float* tab   = (const float*)d_in[15];
    const float* d1w   = (const float*)d_in[16];
    const float* d1b   = (const float*)d_in[17];
    const float* d2w   = (const float*)d_in[18];
    const float* d2b   = (const float*)d_in[19];
    const float* c1w   = (const float*)d_in[20];
    const float* c1b   = (const float*)d_in[21];
    const float* c2w   = (const float*)d_in[22];
    const float* c2b   = (const float*)d_in[23];

    const size_t MR = (size_t)16384 * 512;
    float* ws   = (float*)d_ws;
    float* xmA  = ws;                         // fp32 state A
    float* xmB  = xmA + MR;                   // fp32 state B
    float* x2T  = xmB + MR;                   // d1 output (fp32)
    float* vbuf = x2T + MR;                   // 16384*128
    float* proj = vbuf + (size_t)16384 * 128;
    float* m1m2 = proj + 16384;
    float* dvec = m1m2 + 32768;
    u16* bfb     = (u16*)(dvec + 16384);
    u16* xmA_bf  = bfb;
    u16* xmB_bf  = xmA_bf + MR;
    u16* x1_bf   = xmB_bf + MR;
    u16* x2_bf   = x1_bf + MR;
    u16* x1T_bf  = x2_bf + MR;                // ta output (bf16 only)
    u16* adpT_bf = x1T_bf + MR;               // 16384*64
    u16* ll1w_bf = adpT_bf + (size_t)16384 * 64;
    u16* ll2w_bf = ll1w_bf + 98304;
    u16* gcw_bf  = ll2w_bf + 98304;           // 3*512*1536
    u16* taw_bf  = gcw_bf + 2359296;
    u16* d1w_bf  = taw_bf + 262144;

    k_cvt<<<96,   256, 0, stream>>>(ll1w, ll1w_bf, 98304 / 4);
    k_cvt<<<96,   256, 0, stream>>>(ll2w, ll2w_bf, 98304 / 4);
    k_cvt<<<2304, 256, 0, stream>>>(gcw,  gcw_bf,  2359296 / 4);
    k_cvt<<<256,  256, 0, stream>>>(taw,  taw_bf,  262144 / 4);
    k_cvt<<<128,  256, 0, stream>>>(d1w,  d1w_bf,  131072 / 4);

    k_transpose<<<dim3(8, 256), 256, 0, stream>>>(x, xmA, xmA_bf);
    k_proj<<<256, 64, 0, stream>>>(occ, projw, projb, proj);

    float* cur = xmA;  u16* cur_bf = xmA_bf;
    float* nxt = xmB;  u16* nxt_bf = xmB_bf;
    for (int l = 0; l < 3; ++l) {
        k_m<<<16384, 64, 0, stream>>>(cur, g1w + l * 576, g1b + l, g2w + l * 576, g2b + l, proj, m1m2);
        mfma_gemm<64, 64><<<dim3(256, 2), 256, 0, stream>>>(
            cur_bf, nullptr, nullptr,
            ll1w_bf + (size_t)l * 32768, ll2w_bf + (size_t)l * 32768, 64,
            ll1b + l * 64, ll2b + l * 64, nullptr, vbuf, nullptr, 128, 512, 0);
        k_p<<<16384, 64, 0, stream>>>(vbuf, m1m2, proj);
        k_adp<<<256, 256, 0, stream>>>(vbuf, adpT_bf);
        k_nconv2<<<dim3(4, 256), 256, 0, stream>>>(cur_bf, adpT_bf, x1_bf, x2_bf);
        // hh GEMM: 1024 blocks -> 4 blocks/CU (was 512/2 in R3)
        mfma_gemm<128, 64><<<dim3(128, 8), 256, 0, stream>>>(
            cur_bf, x1_bf, x2_bf,
            gcw_bf + (size_t)l * 786432, gcw_bf + (size_t)l * 786432, 512,
            gcb + l * 512, gcb + l * 512, (l > 0 ? cur : nullptr), nxt, nxt_bf, 512, 1536, 1);
        { float* tf = cur; cur = nxt; nxt = tf; }
        { u16* tb = cur_bf; cur_bf = nxt_bf; nxt_bf = tb; }
    }
    // temporal_agg: bf16-only output
    mfma_gemm<128, 64><<<dim3(128, 8), 256, 0, stream>>>(
        cur_bf, nullptr, nullptr, taw_bf, taw_bf, 512, tab, tab, nullptr, nullptr, x1T_bf, 512, 512, 0);
    // decoder1: fp32 output
    mfma_gemm<128, 64><<<dim3(128, 4), 256, 0, stream>>>(
        x1T_bf, nullptr, nullptr, d1w_bf, d1w_bf, 256, d1b, d1b, nullptr, x2T, nullptr, 256, 512, 1);
    k_dvec<<<4096, 256, 0, stream>>>(x2T, d2w, d2b, dvec);
    k_final<<<256, 64, 0, stream>>>(dvec, c1w, c1b, c2w, c2b, (float*)d_out);
}

// Round 6
// 488.386 us; speedup vs baseline: 1.9444x; 1.1159x over previous
//
#include <hip/hip_runtime.h>

typedef unsigned short u16;
typedef __attribute__((ext_vector_type(8))) short short8;   // 8 bf16
typedef __attribute__((ext_vector_type(4))) float f32x4;

// B=256, N=H=512, C=A=64, L=3, FC=256, FFC=32.  M := B*C = 16384 rows of xm.
// fp32 master state for residual; bf16 shadows feed MFMA GEMMs.

__device__ __forceinline__ u16 f2b(float f) {
    union { float f; unsigned int i; } v; v.f = f;
    unsigned int x = v.i;
    x += 0x7fffu + ((x >> 16) & 1u);   // RNE
    return (u16)(x >> 16);
}
__device__ __forceinline__ float b2f(u16 u) {
    union { unsigned int i; float f; } v;
    v.i = ((unsigned int)u) << 16;
    return v.f;
}
// async global->LDS, 16B per lane; LDS dest = wave-uniform base + lane*16
__device__ __forceinline__ void gl_lds16(const u16* g, u16* l) {
    __builtin_amdgcn_global_load_lds((__attribute__((address_space(1))) void*)(u16*)g,
                                     (__attribute__((address_space(3))) void*)l, 16, 0, 0);
}

// ---------------- fp32 -> bf16 weight conversion
__global__ __launch_bounds__(256) void k_cvt(const float* __restrict__ src, u16* __restrict__ dst, int n4) {
    int i = blockIdx.x * 256 + threadIdx.x;
    if (i < n4) {
        float4 v = ((const float4*)src)[i];
        ushort4 o; o.x = f2b(v.x); o.y = f2b(v.y); o.z = f2b(v.z); o.w = f2b(v.w);
        ((ushort4*)dst)[i] = o;
    }
}

// ---------------- transpose: x[b,n,c] -> xm[(b*64+c)*512+n] fp32 + bf16
__global__ __launch_bounds__(256) void k_transpose(const float* __restrict__ x, float* __restrict__ xm,
                                                   u16* __restrict__ xmb) {
    __shared__ float tile[64][65];
    const int b  = blockIdx.y;
    const int n0 = blockIdx.x * 64;
    const int t  = threadIdx.x;
    const int c  = t & 63;
    const int dn = t >> 6;
#pragma unroll
    for (int i = 0; i < 16; ++i) {
        int nl = dn + i * 4;
        tile[c][nl] = x[((size_t)b * 512 + n0 + nl) * 64 + c];
    }
    __syncthreads();
    const int nl = t & 63;
    const int cb = (t >> 6) * 16;
#pragma unroll
    for (int i = 0; i < 16; ++i) {
        int c2 = cb + i;
        float v = tile[c2][nl];
        size_t idx = ((size_t)b * 64 + c2) * 512 + n0 + nl;
        xm[idx] = v;
        xmb[idx] = f2b(v);
    }
}

// ---------------- proj[b,a]
__global__ __launch_bounds__(64) void k_proj(const float* __restrict__ occ, const float* __restrict__ pw,
                                             const float* __restrict__ pb, float* __restrict__ proj) {
    const int b = blockIdx.x;
    const int a = threadIdx.x;
    const float* ob = occ + (size_t)b * 512;
    const float* wr = pw + (size_t)a * 512;
    float acc = 0.f;
    for (int n = 0; n < 512; ++n) acc += ob[n] * wr[n];
    proj[b * 64 + a] = acc + pb[a];
}

// ---------------- fused gates + P: per row r=(b,c): m1,m2 from bf16 xm, then softmax P1,P2
__global__ __launch_bounds__(64) void k_pm(const u16* __restrict__ xmb,
                                           const float* __restrict__ g1w, const float* __restrict__ g1b,
                                           const float* __restrict__ g2w, const float* __restrict__ g2b,
                                           const float* __restrict__ proj, float* __restrict__ vb) {
    const int r = blockIdx.x;
    const int b = r >> 6, c = r & 63;
    const int lane = threadIdx.x;
    // gate dots: lane covers 8 contiguous k
    const u16* row = xmb + (size_t)r * 512 + lane * 8;
    uint4 xv = *(const uint4*)row;
    const u16* xp = (const u16*)&xv;
    float4 w1a = *(const float4*)(g1w + lane * 8);
    float4 w1b = *(const float4*)(g1w + lane * 8 + 4);
    float4 w2a = *(const float4*)(g2w + lane * 8);
    float4 w2b = *(const float4*)(g2w + lane * 8 + 4);
    const float* w1 = (const float*)&w1a;  // contiguous pair trick not portable; use arrays
    float g1v[8] = {w1a.x, w1a.y, w1a.z, w1a.w, w1b.x, w1b.y, w1b.z, w1b.w};
    float g2v[8] = {w2a.x, w2a.y, w2a.z, w2a.w, w2b.x, w2b.y, w2b.z, w2b.w};
    float a1 = 0.f, a2 = 0.f;
#pragma unroll
    for (int e = 0; e < 8; ++e) {
        float xvf = b2f(xp[e]);
        a1 += xvf * g1v[e];
        a2 += xvf * g2v[e];
    }
    (void)w1;
    a1 += proj[b * 64 + lane] * g1w[512 + lane];   // AATE part
    a2 += proj[b * 64 + c]    * g2w[512 + lane];   // AATE_T part
    for (int off = 32; off; off >>= 1) { a1 += __shfl_xor(a1, off); a2 += __shfl_xor(a2, off); }
    float m1 = tanhf(a1 + g1b[0]); m1 = m1 > 0.f ? m1 : 0.f;
    float m2 = tanhf(a2 + g2b[0]); m2 = m2 > 0.f ? m2 : 0.f;
    // P part
    const int a = lane;
    float s1 = m1 * vb[(size_t)r * 128 + a];       s1 = s1 > 0.f ? s1 : 0.f;
    float s2 = m2 * vb[(size_t)r * 128 + 64 + a];  s2 = s2 > 0.f ? s2 : 0.f;
    float mx1 = s1, mx2 = s2;
    for (int off = 32; off; off >>= 1) { mx1 = fmaxf(mx1, __shfl_xor(mx1, off)); mx2 = fmaxf(mx2, __shfl_xor(mx2, off)); }
    float e1 = expf(s1 - mx1), e2 = expf(s2 - mx2);
    float su1 = e1, su2 = e2;
    for (int off = 32; off; off >>= 1) { su1 += __shfl_xor(su1, off); su2 += __shfl_xor(su2, off); }
    vb[(size_t)r * 128 + a]      = proj[b * 64 + a] + e1 / su1;
    vb[(size_t)r * 128 + 64 + a] = proj[b * 64 + c] + e2 / su2;
}

// ---------------- adp -> transposed bf16: adpT[(b*64+v)*64 + c] = adp[c][v]
__global__ __launch_bounds__(256) void k_adp(const float* __restrict__ vb, u16* __restrict__ adpT) {
    __shared__ float P1s[64][64];
    __shared__ float P2s[64][65];
    __shared__ __align__(16) u16 Tl[64 * 72];
    const int b = blockIdx.x;
    const int t = threadIdx.x;
#pragma unroll
    for (int i = 0; i < 16; ++i) {
        int idx = t + 256 * i;
        int c = idx >> 6, a = idx & 63;
        P1s[c][a] = vb[((size_t)b * 64 + c) * 128 + a];
        P2s[c][a] = vb[((size_t)b * 64 + c) * 128 + 64 + a];
    }
    __syncthreads();
    const int lane = t & 63;   // v (softmax dim)
    const int w = t >> 6;
    for (int ci = 0; ci < 16; ++ci) {
        int c = w + ci * 4;
        float s = 0.f;
        for (int a = 0; a < 64; ++a) s += P1s[c][a] * P2s[lane][a];
        s = fmaxf(s, 0.f);
        float mx = s;
        for (int off = 32; off; off >>= 1) mx = fmaxf(mx, __shfl_xor(mx, off));
        float e = expf(s - mx);
        float su = e;
        for (int off = 32; off; off >>= 1) su += __shfl_xor(su, off);
        Tl[lane * 72 + c] = f2b(e / su);     // transposed: row v, col c
    }
    __syncthreads();
    const int v = t >> 2, ck = (t & 3) * 16;
    u16* dst = adpT + ((size_t)b * 64 + v) * 64 + ck;
    *(uint4*)dst       = *(const uint4*)&Tl[v * 72 + ck];
    *(uint4*)(dst + 8) = *(const uint4*)&Tl[v * 72 + ck + 8];
}

// ---------------- fused double nconv via MFMA: x1 = adp^T X, x2 = adp^T x1 (per b, n-tile 128)
__global__ __launch_bounds__(256) void k_nconv2(const u16* __restrict__ Xbf, const u16* __restrict__ adpT,
                                                u16* __restrict__ x1bf, u16* __restrict__ x2bf) {
    __shared__ __align__(16) u16 Ts[64 * 72];    // adpT rows v, cols c (k)
    __shared__ __align__(16) u16 Xs[128 * 72];   // XT rows n-local, cols c; reused for x1T
    const int b  = blockIdx.y;
    const int n0 = blockIdx.x * 128;
    const int t  = threadIdx.x;
    const int lane = t & 63, w = t >> 6;
    const int lrow = lane & 15, q = lane >> 4;
    const int wn = w * 32;

    { // stage adpT (already transposed, coalesced)
        int v = t >> 2, ck = (t & 3) * 8;
        const u16* src = adpT + ((size_t)b * 64 + v) * 64;
        *(uint4*)&Ts[v * 72 + ck]      = *(const uint4*)(src + ck);
        *(uint4*)&Ts[v * 72 + ck + 32] = *(const uint4*)(src + ck + 32);
    }
    { // stage X with in-LDS transpose: Xs[n][c]
        int c = t >> 2;
        const u16* xr = Xbf + ((size_t)b * 64 + c) * 512 + n0;
#pragma unroll
        for (int j = 0; j < 4; ++j) {
            int nn = j * 32 + (t & 3) * 8;
            uint4 vv = *(const uint4*)(xr + nn);
            const u16* pv = (const u16*)&vv;
#pragma unroll
            for (int e = 0; e < 8; ++e) Xs[(nn + e) * 72 + c] = pv[e];
        }
    }
    __syncthreads();

    const f32x4 zero = {0.f, 0.f, 0.f, 0.f};
    f32x4 acc[4][2];
#pragma unroll
    for (int mt = 0; mt < 4; ++mt)
#pragma unroll
        for (int nt = 0; nt < 2; ++nt) acc[mt][nt] = zero;

#pragma unroll
    for (int ks = 0; ks < 2; ++ks) {
        short8 af[4], bfr[2];
#pragma unroll
        for (int mt = 0; mt < 4; ++mt) af[mt]  = *(const short8*)&Ts[(mt * 16 + lrow) * 72 + ks * 32 + q * 8];
#pragma unroll
        for (int nt = 0; nt < 2; ++nt) bfr[nt] = *(const short8*)&Xs[(wn + nt * 16 + lrow) * 72 + ks * 32 + q * 8];
#pragma unroll
        for (int mt = 0; mt < 4; ++mt)
#pragma unroll
            for (int nt = 0; nt < 2; ++nt)
                acc[mt][nt] = __builtin_amdgcn_mfma_f32_16x16x32_bf16(af[mt], bfr[nt], acc[mt][nt], 0, 0, 0);
    }
    __syncthreads();   // all Xs reads done

    // write x1 -> global and x1^T -> Xs (for round 2)
#pragma unroll
    for (int mt = 0; mt < 4; ++mt)
#pragma unroll
        for (int nt = 0; nt < 2; ++nt) {
            int nl = wn + nt * 16 + lrow;
            ushort4 u;
            u.x = f2b(acc[mt][nt][0]); u.y = f2b(acc[mt][nt][1]);
            u.z = f2b(acc[mt][nt][2]); u.w = f2b(acc[mt][nt][3]);
            *(ushort4*)&Xs[nl * 72 + mt * 16 + q * 4] = u;
#pragma unroll
            for (int i = 0; i < 4; ++i)
                x1bf[((size_t)(b * 64 + mt * 16 + q * 4 + i)) * 512 + n0 + nl] = ((const u16*)&u)[i];
        }
    __syncthreads();

    f32x4 acc2[4][2];
#pragma unroll
    for (int mt = 0; mt < 4; ++mt)
#pragma unroll
        for (int nt = 0; nt < 2; ++nt) acc2[mt][nt] = zero;
#pragma unroll
    for (int ks = 0; ks < 2; ++ks) {
        short8 af[4], bfr[2];
#pragma unroll
        for (int mt = 0; mt < 4; ++mt) af[mt]  = *(const short8*)&Ts[(mt * 16 + lrow) * 72 + ks * 32 + q * 8];
#pragma unroll
        for (int nt = 0; nt < 2; ++nt) bfr[nt] = *(const short8*)&Xs[(wn + nt * 16 + lrow) * 72 + ks * 32 + q * 8];
#pragma unroll
        for (int mt = 0; mt < 4; ++mt)
#pragma unroll
            for (int nt = 0; nt < 2; ++nt)
                acc2[mt][nt] = __builtin_amdgcn_mfma_f32_16x16x32_bf16(af[mt], bfr[nt], acc2[mt][nt], 0, 0, 0);
    }
#pragma unroll
    for (int mt = 0; mt < 4; ++mt)
#pragma unroll
        for (int nt = 0; nt < 2; ++nt) {
            int nl = wn + nt * 16 + lrow;
#pragma unroll
            for (int i = 0; i < 4; ++i)
                x2bf[((size_t)(b * 64 + mt * 16 + q * 4 + i)) * 512 + n0 + nl] = f2b(acc2[mt][nt][i]);
        }
}

// ---------------- MFMA GEMM with global_load_lds staging + swizzled 64B-row LDS layout.
// LDS row = 32 shorts (64B), 4 chunks of 8 elems; data chunk c of row stored at pos (c+(row>>1))&3.
// DMA: one wave-instr fills 16 rows (1KB contiguous); lane i -> row16=i>>2, pos=i&3.
template<int BM, int BN>
__global__ __launch_bounds__(256) void mfma_gemm(
    const u16* __restrict__ A0, const u16* __restrict__ A1, const u16* __restrict__ A2,
    const u16* __restrict__ W0, const u16* __restrict__ W1, int nsplit,
    const float* __restrict__ bias0, const float* __restrict__ bias1,
    const float* __restrict__ res, float* __restrict__ out, u16* __restrict__ outbf,
    int N, int K, int relu)
{
    constexpr int MT = BM / 32;       // m-tiles of 16 per wave (wave tile BM/2)
    constexpr int NT = BN / 32;
    constexpr int AI = BM / 16;       // A DMA wave-instructions per iter
    constexpr int BI = BN / 16;
    __shared__ __align__(16) u16 As[BM * 32];
    __shared__ __align__(16) u16 Bs[BN * 32];
    const int t    = threadIdx.x;
    const int m0   = blockIdx.x * BM;
    const int n0   = blockIdx.y * BN;
    const int lane = t & 63;
    const int w    = t >> 6;
    const int wm   = (w >> 1) * (BM / 2);
    const int wn   = (w & 1) * (BN / 2);
    const int lrow = lane & 15;
    const int q    = lane >> 4;
    const int sr16 = lane >> 2;       // row within 16-row DMA group
    const int sp   = lane & 3;        // 16B pos within 64B row

    const f32x4 zero = {0.f, 0.f, 0.f, 0.f};
    f32x4 acc[MT][NT];
#pragma unroll
    for (int i = 0; i < MT; ++i)
#pragma unroll
        for (int j = 0; j < NT; ++j) acc[i][j] = zero;

    for (int k0 = 0; k0 < K; k0 += 32) {
        const u16* Abase = A0;
        int kloc = k0;
        if (K > 512) {
            int seg = k0 >> 9;
            Abase = (seg == 0) ? A0 : ((seg == 1) ? A1 : A2);
            kloc = k0 & 511;
        }
#pragma unroll
        for (int jj = 0; jj < AI / 4; ++jj) {
            int j = jj * 4 + w;
            int row = j * 16 + sr16;
            int c = (sp - (row >> 1)) & 3;
            gl_lds16(Abase + (size_t)(m0 + row) * 512 + kloc + c * 8, As + j * 512);
        }
#pragma unroll
        for (int jj = 0; jj < BI / 4; ++jj) {
            int j = jj * 4 + w;
            int row = j * 16 + sr16;
            int n = n0 + row;
            const u16* wr = (n < nsplit) ? (W0 + (size_t)n * K) : (W1 + (size_t)(n - nsplit) * K);
            int c = (sp - (row >> 1)) & 3;
            gl_lds16(wr + k0 + c * 8, Bs + j * 512);
        }
        __syncthreads();   // drains vmcnt(0): DMA'd tile visible

        short8 af[MT], bfr[NT];
#pragma unroll
        for (int mt = 0; mt < MT; ++mt) {
            int row = wm + mt * 16 + lrow;
            int p = (q + (row >> 1)) & 3;
            af[mt] = *(const short8*)&As[row * 32 + p * 8];
        }
#pragma unroll
        for (int nt = 0; nt < NT; ++nt) {
            int row = wn + nt * 16 + lrow;
            int p = (q + (row >> 1)) & 3;
            bfr[nt] = *(const short8*)&Bs[row * 32 + p * 8];
        }
#pragma unroll
        for (int mt = 0; mt < MT; ++mt)
#pragma unroll
            for (int nt = 0; nt < NT; ++nt)
                acc[mt][nt] = __builtin_amdgcn_mfma_f32_16x16x32_bf16(af[mt], bfr[nt], acc[mt][nt], 0, 0, 0);
        __syncthreads();   // reads done before next iter's DMA overwrites
    }

#pragma unroll
    for (int mt = 0; mt < MT; ++mt) {
        int mb = m0 + wm + mt * 16 + q * 4;
#pragma unroll
        for (int nt = 0; nt < NT; ++nt) {
            int n = n0 + wn + nt * 16 + lrow;
            float bvv = (n < nsplit) ? bias0[n] : bias1[n - nsplit];
#pragma unroll
            for (int i = 0; i < 4; ++i) {
                float v = acc[mt][nt][i] + bvv;
                if (relu) v = fmaxf(v, 0.f);
                if (res) v += res[(size_t)(mb + i) * N + n];
                if (out) out[(size_t)(mb + i) * N + n] = v;
                if (outbf) outbf[(size_t)(mb + i) * N + n] = f2b(v);
            }
        }
    }
}

// ---------------- dvec[r] = t[r,:256] . d2_w + d2_b
__global__ __launch_bounds__(256) void k_dvec(const float* __restrict__ tmat, const float* __restrict__ d2w,
                                              const float* __restrict__ d2b, float* __restrict__ dvec) {
    const int r = blockIdx.x * 4 + (threadIdx.x >> 6);
    const int lane = threadIdx.x & 63;
    const float* row = tmat + (size_t)r * 256;
    float acc = 0.f;
    for (int f = lane; f < 256; f += 64) acc += row[f] * d2w[f];
    for (int off = 32; off; off >>= 1) acc += __shfl_xor(acc, off);
    if (lane == 0) dvec[r] = acc + d2b[0];
}

// ---------------- channel decoder + abs
__global__ __launch_bounds__(64) void k_final(const float* __restrict__ dvec, const float* __restrict__ c1w,
                                              const float* __restrict__ c1b, const float* __restrict__ c2w,
                                              const float* __restrict__ c2b, float* __restrict__ out) {
    const int b = blockIdx.x;
    const int f = threadIdx.x;
    float part = 0.f;
    if (f < 32) {
        float acc = c1b[f];
        const float* dr = dvec + b * 64;
        for (int c = 0; c < 64; ++c) acc += dr[c] * c1w[f * 64 + c];
        acc = acc > 0.f ? acc : 0.f;
        part = acc * c2w[f];
    }
    for (int off = 32; off; off >>= 1) part += __shfl_xor(part, off);
    if (f == 0) out[b] = fabsf(part + c2b[0]);
}

extern "C" void kernel_launch(void* const* d_in, const int* in_sizes, int n_in,
                              void* d_out, int out_size, void* d_ws, size_t ws_size,
                              hipStream_t stream) {
    const float* x     = (const float*)d_in[0];
    const float* occ   = (const float*)d_in[1];
    const float* projw = (const float*)d_in[2];
    const float* projb = (const float*)d_in[3];
    const float* ll1w  = (const float*)d_in[4];
    const float* ll1b  = (const float*)d_in[5];
    const float* ll2w  = (const float*)d_in[6];
    const float* ll2b  = (const float*)d_in[7];
    const float* g1w   = (const float*)d_in[8];
    const float* g1b   = (const float*)d_in[9];
    const float* g2w   = (const float*)d_in[10];
    const float* g2b   = (const float*)d_in[11];
    const float* gcw   = (const float*)d_in[12];
    const float* gcb   = (const float*)d_in[13];
    const float* taw   = (const float*)d_in[14];
    const float* tab   = (const float*)d_in[15];
    const float* d1w   = (const float*)d_in[16];
    const float* d1b   = (const float*)d_in[17];
    const float* d2w   = (const float*)d_in[18];
    const float* d2b   = (const float*)d_in[19];
    const float* c1w   = (const float*)d_in[20];
    const float* c1b   = (const float*)d_in[21];
    const float* c2w   = (const float*)d_in[22];
    const float* c2b   = (const float*)d_in[23];

    const size_t MR = (size_t)16384 * 512;
    float* ws   = (float*)d_ws;
    float* xmA  = ws;                         // fp32 state A
    float* xmB  = xmA + MR;                   // fp32 state B
    float* x2T  = xmB + MR;                   // d1 output (fp32)
    float* vbuf = x2T + MR;                   // 16384*128
    float* proj = vbuf + (size_t)16384 * 128;
    float* m1m2 = proj + 16384;               // (unused slot, kept for layout stability)
    float* dvec = m1m2 + 32768;
    u16* bfb     = (u16*)(dvec + 16384);
    u16* xmA_bf  = bfb;
    u16* xmB_bf  = xmA_bf + MR;
    u16* x1_bf   = xmB_bf + MR;
    u16* x2_bf   = x1_bf + MR;
    u16* x1T_bf  = x2_bf + MR;                // ta output (bf16 only)
    u16* adpT_bf = x1T_bf + MR;               // 16384*64
    u16* ll1w_bf = adpT_bf + (size_t)16384 * 64;
    u16* ll2w_bf = ll1w_bf + 98304;
    u16* gcw_bf  = ll2w_bf + 98304;           // 3*512*1536
    u16* taw_bf  = gcw_bf + 2359296;
    u16* d1w_bf  = taw_bf + 262144;

    k_cvt<<<96,   256, 0, stream>>>(ll1w, ll1w_bf, 98304 / 4);
    k_cvt<<<96,   256, 0, stream>>>(ll2w, ll2w_bf, 98304 / 4);
    k_cvt<<<2304, 256, 0, stream>>>(gcw,  gcw_bf,  2359296 / 4);
    k_cvt<<<256,  256, 0, stream>>>(taw,  taw_bf,  262144 / 4);
    k_cvt<<<128,  256, 0, stream>>>(d1w,  d1w_bf,  131072 / 4);

    k_transpose<<<dim3(8, 256), 256, 0, stream>>>(x, xmA, xmA_bf);
    k_proj<<<256, 64, 0, stream>>>(occ, projw, projb, proj);

    float* cur = xmA;  u16* cur_bf = xmA_bf;
    float* nxt = xmB;  u16* nxt_bf = xmB_bf;
    for (int l = 0; l < 3; ++l) {
        mfma_gemm<64, 64><<<dim3(256, 2), 256, 0, stream>>>(
            cur_bf, nullptr, nullptr,
            ll1w_bf + (size_t)l * 32768, ll2w_bf + (size_t)l * 32768, 64,
            ll1b + l * 64, ll2b + l * 64, nullptr, vbuf, nullptr, 128, 512, 0);
        k_pm<<<16384, 64, 0, stream>>>(cur_bf, g1w + l * 576, g1b + l, g2w + l * 576, g2b + l, proj, vbuf);
        k_adp<<<256, 256, 0, stream>>>(vbuf, adpT_bf);
        k_nconv2<<<dim3(4, 256), 256, 0, stream>>>(cur_bf, adpT_bf, x1_bf, x2_bf);
        mfma_gemm<128, 64><<<dim3(128, 8), 256, 0, stream>>>(
            cur_bf, x1_bf, x2_bf,
            gcw_bf + (size_t)l * 786432, gcw_bf + (size_t)l * 786432, 512,
            gcb + l * 512, gcb + l * 512, (l > 0 ? cur : nullptr), nxt, nxt_bf, 512, 1536, 1);
        { float* tf = cur; cur = nxt; nxt = tf; }
        { u16* tb = cur_bf; cur_bf = nxt_bf; nxt_bf = tb; }
    }
    // temporal_agg: bf16-only output
    mfma_gemm<128, 64><<<dim3(128, 8), 256, 0, stream>>>(
        cur_bf, nullptr, nullptr, taw_bf, taw_bf, 512, tab, tab, nullptr, nullptr, x1T_bf, 512, 512, 0);
    // decoder1: fp32 output
    mfma_gemm<64, 64><<<dim3(256, 4), 256, 0, stream>>>(
        x1T_bf, nullptr, nullptr, d1w_bf, d1w_bf, 256, d1b, d1b, nullptr, x2T, nullptr, 256, 512, 1);
    k_dvec<<<4096, 256, 0, stream>>>(x2T, d2w, d2b, dvec);
    k_final<<<256, 64, 0, stream>>>(dvec, c1w, c1b, c2w, c2b, (float*)d_out);
}

// Round 7
// 477.119 us; speedup vs baseline: 1.9904x; 1.0236x over previous
//
#include <hip/hip_runtime.h>

typedef unsigned short u16;
typedef __attribute__((ext_vector_type(8))) short short8;   // 8 bf16
typedef __attribute__((ext_vector_type(4))) float f32x4;

// B=256, N=H=512, C=A=64, L=3, FC=256, FFC=32.  M := B*C = 16384 rows of xm.
// fp32 master state for residual; bf16 shadows feed MFMA GEMMs.

__device__ __forceinline__ u16 f2b(float f) {
    union { float f; unsigned int i; } v; v.f = f;
    unsigned int x = v.i;
    x += 0x7fffu + ((x >> 16) & 1u);   // RNE
    return (u16)(x >> 16);
}
__device__ __forceinline__ float b2f(u16 u) {
    union { unsigned int i; float f; } v;
    v.i = ((unsigned int)u) << 16;
    return v.f;
}
// async global->LDS, 16B per lane; LDS dest = wave-uniform base + lane*16
__device__ __forceinline__ void gl_lds16(const u16* g, u16* l) {
    __builtin_amdgcn_global_load_lds((__attribute__((address_space(1))) void*)(u16*)g,
                                     (__attribute__((address_space(3))) void*)l, 16, 0, 0);
}

// ---------------- fp32 -> bf16 weight conversion
__global__ __launch_bounds__(256) void k_cvt(const float* __restrict__ src, u16* __restrict__ dst, int n4) {
    int i = blockIdx.x * 256 + threadIdx.x;
    if (i < n4) {
        float4 v = ((const float4*)src)[i];
        ushort4 o; o.x = f2b(v.x); o.y = f2b(v.y); o.z = f2b(v.z); o.w = f2b(v.w);
        ((ushort4*)dst)[i] = o;
    }
}

// ---------------- transpose: x[b,n,c] -> xm[(b*64+c)*512+n] fp32 + bf16
__global__ __launch_bounds__(256) void k_transpose(const float* __restrict__ x, float* __restrict__ xm,
                                                   u16* __restrict__ xmb) {
    __shared__ float tile[64][65];
    const int b  = blockIdx.y;
    const int n0 = blockIdx.x * 64;
    const int t  = threadIdx.x;
    const int c  = t & 63;
    const int dn = t >> 6;
#pragma unroll
    for (int i = 0; i < 16; ++i) {
        int nl = dn + i * 4;
        tile[c][nl] = x[((size_t)b * 512 + n0 + nl) * 64 + c];
    }
    __syncthreads();
    const int nl = t & 63;
    const int cb = (t >> 6) * 16;
#pragma unroll
    for (int i = 0; i < 16; ++i) {
        int c2 = cb + i;
        float v = tile[c2][nl];
        size_t idx = ((size_t)b * 64 + c2) * 512 + n0 + nl;
        xm[idx] = v;
        xmb[idx] = f2b(v);
    }
}

// ---------------- proj[b,a]
__global__ __launch_bounds__(64) void k_proj(const float* __restrict__ occ, const float* __restrict__ pw,
                                             const float* __restrict__ pb, float* __restrict__ proj) {
    const int b = blockIdx.x;
    const int a = threadIdx.x;
    const float* ob = occ + (size_t)b * 512;
    const float* wr = pw + (size_t)a * 512;
    float acc = 0.f;
    for (int n = 0; n < 512; ++n) acc += ob[n] * wr[n];
    proj[b * 64 + a] = acc + pb[a];
}

// ---------------- fused gates + P: per row r=(b,c): m1,m2 from bf16 xm, then softmax P1,P2
__global__ __launch_bounds__(64) void k_pm(const u16* __restrict__ xmb,
                                           const float* __restrict__ g1w, const float* __restrict__ g1b,
                                           const float* __restrict__ g2w, const float* __restrict__ g2b,
                                           const float* __restrict__ proj, float* __restrict__ vb) {
    const int r = blockIdx.x;
    const int b = r >> 6, c = r & 63;
    const int lane = threadIdx.x;
    const u16* row = xmb + (size_t)r * 512 + lane * 8;
    uint4 xv = *(const uint4*)row;
    const u16* xp = (const u16*)&xv;
    float4 w1a = *(const float4*)(g1w + lane * 8);
    float4 w1b = *(const float4*)(g1w + lane * 8 + 4);
    float4 w2a = *(const float4*)(g2w + lane * 8);
    float4 w2b = *(const float4*)(g2w + lane * 8 + 4);
    float g1v[8] = {w1a.x, w1a.y, w1a.z, w1a.w, w1b.x, w1b.y, w1b.z, w1b.w};
    float g2v[8] = {w2a.x, w2a.y, w2a.z, w2a.w, w2b.x, w2b.y, w2b.z, w2b.w};
    float a1 = 0.f, a2 = 0.f;
#pragma unroll
    for (int e = 0; e < 8; ++e) {
        float xvf = b2f(xp[e]);
        a1 += xvf * g1v[e];
        a2 += xvf * g2v[e];
    }
    a1 += proj[b * 64 + lane] * g1w[512 + lane];   // AATE part
    a2 += proj[b * 64 + c]    * g2w[512 + lane];   // AATE_T part
    for (int off = 32; off; off >>= 1) { a1 += __shfl_xor(a1, off); a2 += __shfl_xor(a2, off); }
    float m1 = tanhf(a1 + g1b[0]); m1 = m1 > 0.f ? m1 : 0.f;
    float m2 = tanhf(a2 + g2b[0]); m2 = m2 > 0.f ? m2 : 0.f;
    const int a = lane;
    float s1 = m1 * vb[(size_t)r * 128 + a];       s1 = s1 > 0.f ? s1 : 0.f;
    float s2 = m2 * vb[(size_t)r * 128 + 64 + a];  s2 = s2 > 0.f ? s2 : 0.f;
    float mx1 = s1, mx2 = s2;
    for (int off = 32; off; off >>= 1) { mx1 = fmaxf(mx1, __shfl_xor(mx1, off)); mx2 = fmaxf(mx2, __shfl_xor(mx2, off)); }
    float e1 = expf(s1 - mx1), e2 = expf(s2 - mx2);
    float su1 = e1, su2 = e2;
    for (int off = 32; off; off >>= 1) { su1 += __shfl_xor(su1, off); su2 += __shfl_xor(su2, off); }
    vb[(size_t)r * 128 + a]      = proj[b * 64 + a] + e1 / su1;
    vb[(size_t)r * 128 + 64 + a] = proj[b * 64 + c] + e2 / su2;
}

// ---------------- adp -> transposed bf16: adpT[(b*64+v)*64 + c] = adp[c][v]
__global__ __launch_bounds__(256) void k_adp(const float* __restrict__ vb, u16* __restrict__ adpT) {
    __shared__ float P1s[64][64];
    __shared__ float P2s[64][65];
    __shared__ __align__(16) u16 Tl[64 * 72];
    const int b = blockIdx.x;
    const int t = threadIdx.x;
#pragma unroll
    for (int i = 0; i < 16; ++i) {
        int idx = t + 256 * i;
        int c = idx >> 6, a = idx & 63;
        P1s[c][a] = vb[((size_t)b * 64 + c) * 128 + a];
        P2s[c][a] = vb[((size_t)b * 64 + c) * 128 + 64 + a];
    }
    __syncthreads();
    const int lane = t & 63;   // v (softmax dim)
    const int w = t >> 6;
    for (int ci = 0; ci < 16; ++ci) {
        int c = w + ci * 4;
        float s = 0.f;
        for (int a = 0; a < 64; ++a) s += P1s[c][a] * P2s[lane][a];
        s = fmaxf(s, 0.f);
        float mx = s;
        for (int off = 32; off; off >>= 1) mx = fmaxf(mx, __shfl_xor(mx, off));
        float e = expf(s - mx);
        float su = e;
        for (int off = 32; off; off >>= 1) su += __shfl_xor(su, off);
        Tl[lane * 72 + c] = f2b(e / su);     // transposed: row v, col c
    }
    __syncthreads();
    const int v = t >> 2, ck = (t & 3) * 16;
    u16* dst = adpT + ((size_t)b * 64 + v) * 64 + ck;
    *(uint4*)dst       = *(const uint4*)&Tl[v * 72 + ck];
    *(uint4*)(dst + 8) = *(const uint4*)&Tl[v * 72 + ck + 8];
}

// ---------------- fused double nconv via MFMA: x1 = adp^T X, x2 = adp^T x1 (per b, n-tile 128)
__global__ __launch_bounds__(256) void k_nconv2(const u16* __restrict__ Xbf, const u16* __restrict__ adpT,
                                                u16* __restrict__ x1bf, u16* __restrict__ x2bf) {
    __shared__ __align__(16) u16 Ts[64 * 72];    // adpT rows v, cols c (k)
    __shared__ __align__(16) u16 Xs[128 * 72];   // XT rows n-local, cols c; reused for x1T
    const int b  = blockIdx.y;
    const int n0 = blockIdx.x * 128;
    const int t  = threadIdx.x;
    const int lane = t & 63, w = t >> 6;
    const int lrow = lane & 15, q = lane >> 4;
    const int wn = w * 32;

    { // stage adpT (already transposed, coalesced)
        int v = t >> 2, ck = (t & 3) * 8;
        const u16* src = adpT + ((size_t)b * 64 + v) * 64;
        *(uint4*)&Ts[v * 72 + ck]      = *(const uint4*)(src + ck);
        *(uint4*)&Ts[v * 72 + ck + 32] = *(const uint4*)(src + ck + 32);
    }
    { // stage X with in-LDS transpose: Xs[n][c]
        int c = t >> 2;
        const u16* xr = Xbf + ((size_t)b * 64 + c) * 512 + n0;
#pragma unroll
        for (int j = 0; j < 4; ++j) {
            int nn = j * 32 + (t & 3) * 8;
            uint4 vv = *(const uint4*)(xr + nn);
            const u16* pv = (const u16*)&vv;
#pragma unroll
            for (int e = 0; e < 8; ++e) Xs[(nn + e) * 72 + c] = pv[e];
        }
    }
    __syncthreads();

    const f32x4 zero = {0.f, 0.f, 0.f, 0.f};
    f32x4 acc[4][2];
#pragma unroll
    for (int mt = 0; mt < 4; ++mt)
#pragma unroll
        for (int nt = 0; nt < 2; ++nt) acc[mt][nt] = zero;

#pragma unroll
    for (int ks = 0; ks < 2; ++ks) {
        short8 af[4], bfr[2];
#pragma unroll
        for (int mt = 0; mt < 4; ++mt) af[mt]  = *(const short8*)&Ts[(mt * 16 + lrow) * 72 + ks * 32 + q * 8];
#pragma unroll
        for (int nt = 0; nt < 2; ++nt) bfr[nt] = *(const short8*)&Xs[(wn + nt * 16 + lrow) * 72 + ks * 32 + q * 8];
#pragma unroll
        for (int mt = 0; mt < 4; ++mt)
#pragma unroll
            for (int nt = 0; nt < 2; ++nt)
                acc[mt][nt] = __builtin_amdgcn_mfma_f32_16x16x32_bf16(af[mt], bfr[nt], acc[mt][nt], 0, 0, 0);
    }
    __syncthreads();   // all Xs reads done

    // write x1 -> global and x1^T -> Xs (for round 2)
#pragma unroll
    for (int mt = 0; mt < 4; ++mt)
#pragma unroll
        for (int nt = 0; nt < 2; ++nt) {
            int nl = wn + nt * 16 + lrow;
            ushort4 u;
            u.x = f2b(acc[mt][nt][0]); u.y = f2b(acc[mt][nt][1]);
            u.z = f2b(acc[mt][nt][2]); u.w = f2b(acc[mt][nt][3]);
            *(ushort4*)&Xs[nl * 72 + mt * 16 + q * 4] = u;
#pragma unroll
            for (int i = 0; i < 4; ++i)
                x1bf[((size_t)(b * 64 + mt * 16 + q * 4 + i)) * 512 + n0 + nl] = ((const u16*)&u)[i];
        }
    __syncthreads();

    f32x4 acc2[4][2];
#pragma unroll
    for (int mt = 0; mt < 4; ++mt)
#pragma unroll
        for (int nt = 0; nt < 2; ++nt) acc2[mt][nt] = zero;
#pragma unroll
    for (int ks = 0; ks < 2; ++ks) {
        short8 af[4], bfr[2];
#pragma unroll
        for (int mt = 0; mt < 4; ++mt) af[mt]  = *(const short8*)&Ts[(mt * 16 + lrow) * 72 + ks * 32 + q * 8];
#pragma unroll
        for (int nt = 0; nt < 2; ++nt) bfr[nt] = *(const short8*)&Xs[(wn + nt * 16 + lrow) * 72 + ks * 32 + q * 8];
#pragma unroll
        for (int mt = 0; mt < 4; ++mt)
#pragma unroll
            for (int nt = 0; nt < 2; ++nt)
                acc2[mt][nt] = __builtin_amdgcn_mfma_f32_16x16x32_bf16(af[mt], bfr[nt], acc2[mt][nt], 0, 0, 0);
    }
#pragma unroll
    for (int mt = 0; mt < 4; ++mt)
#pragma unroll
        for (int nt = 0; nt < 2; ++nt) {
            int nl = wn + nt * 16 + lrow;
#pragma unroll
            for (int i = 0; i < 4; ++i)
                x2bf[((size_t)(b * 64 + mt * 16 + q * 4 + i)) * 512 + n0 + nl] = f2b(acc2[mt][nt][i]);
        }
}

// ---------------- MFMA GEMM, double-buffered global_load_lds + swizzled 64B-row LDS layout.
// LDS row = 32 shorts (64B), 4 chunks of 8; data chunk c of row stored at pos (c+(row>>1))&3.
// Pipeline: barrier(drains DMA of cur) -> issue DMA(next)->other buf -> compute(cur). 1 barrier/iter.
template<int BM, int BN>
__global__ __launch_bounds__(256) void mfma_gemm(
    const u16* __restrict__ A0, const u16* __restrict__ A1, const u16* __restrict__ A2,
    const u16* __restrict__ W0, const u16* __restrict__ W1, int nsplit,
    const float* __restrict__ bias0, const float* __restrict__ bias1,
    const float* __restrict__ res, float* __restrict__ out, u16* __restrict__ outbf,
    int N, int K, int relu)
{
    constexpr int MT = BM / 32;       // m-tiles of 16 per wave (wave tile BM/2)
    constexpr int NT = BN / 32;
    constexpr int AI = BM / 16;       // A DMA wave-instructions per iter (across 4 waves)
    constexpr int BI = BN / 16;
    constexpr int TILE = (BM + BN) * 32;
    __shared__ __align__(16) u16 SM[2 * TILE];
    const int t    = threadIdx.x;
    const int m0   = blockIdx.x * BM;
    const int n0   = blockIdx.y * BN;
    const int lane = t & 63;
    const int w    = t >> 6;
    const int wm   = (w >> 1) * (BM / 2);
    const int wn   = (w & 1) * (BN / 2);
    const int lrow = lane & 15;
    const int q    = lane >> 4;
    const int sr16 = lane >> 2;       // row within 16-row DMA group
    const int sp   = lane & 3;        // 16B pos within 64B row

    auto stage = [&](int k0, int buf) {
        u16* As = SM + buf * TILE;
        u16* Bs = As + BM * 32;
        const u16* Abase = A0;
        int kloc = k0;
        if (K > 512) {
            int seg = k0 >> 9;
            Abase = (seg == 0) ? A0 : ((seg == 1) ? A1 : A2);
            kloc = k0 & 511;
        }
#pragma unroll
        for (int jj = 0; jj < AI / 4; ++jj) {
            int j = jj * 4 + w;
            int row = j * 16 + sr16;
            int c = (sp - (row >> 1)) & 3;
            gl_lds16(Abase + (size_t)(m0 + row) * 512 + kloc + c * 8, As + j * 512);
        }
#pragma unroll
        for (int jj = 0; jj < BI / 4; ++jj) {
            int j = jj * 4 + w;
            int row = j * 16 + sr16;
            int n = n0 + row;
            const u16* wr = (n < nsplit) ? (W0 + (size_t)n * K) : (W1 + (size_t)(n - nsplit) * K);
            int c = (sp - (row >> 1)) & 3;
            gl_lds16(wr + k0 + c * 8, Bs + j * 512);
        }
    };

    const f32x4 zero = {0.f, 0.f, 0.f, 0.f};
    f32x4 acc[MT][NT];
#pragma unroll
    for (int i = 0; i < MT; ++i)
#pragma unroll
        for (int j = 0; j < NT; ++j) acc[i][j] = zero;

    stage(0, 0);
    const int iters = K >> 5;
    int buf = 0;
    for (int it = 0; it < iters; ++it) {
        __syncthreads();               // drains vmcnt -> tile(it) in SM[buf] visible; orders prior reads
        if (it + 1 < iters) stage((it + 1) * 32, buf ^ 1);   // DMA next tile under compute
        const u16* As = SM + buf * TILE;
        const u16* Bs = As + BM * 32;
        short8 af[MT], bfr[NT];
#pragma unroll
        for (int mt = 0; mt < MT; ++mt) {
            int row = wm + mt * 16 + lrow;
            int p = (q + (row >> 1)) & 3;
            af[mt] = *(const short8*)&As[row * 32 + p * 8];
        }
#pragma unroll
        for (int nt = 0; nt < NT; ++nt) {
            int row = wn + nt * 16 + lrow;
            int p = (q + (row >> 1)) & 3;
            bfr[nt] = *(const short8*)&Bs[row * 32 + p * 8];
        }
#pragma unroll
        for (int mt = 0; mt < MT; ++mt)
#pragma unroll
            for (int nt = 0; nt < NT; ++nt)
                acc[mt][nt] = __builtin_amdgcn_mfma_f32_16x16x32_bf16(af[mt], bfr[nt], acc[mt][nt], 0, 0, 0);
        buf ^= 1;
    }

#pragma unroll
    for (int mt = 0; mt < MT; ++mt) {
        int mb = m0 + wm + mt * 16 + q * 4;
#pragma unroll
        for (int nt = 0; nt < NT; ++nt) {
            int n = n0 + wn + nt * 16 + lrow;
            float bvv = (n < nsplit) ? bias0[n] : bias1[n - nsplit];
#pragma unroll
            for (int i = 0; i < 4; ++i) {
                float v = acc[mt][nt][i] + bvv;
                if (relu) v = fmaxf(v, 0.f);
                if (res) v += res[(size_t)(mb + i) * N + n];
                if (out) out[(size_t)(mb + i) * N + n] = v;
                if (outbf) outbf[(size_t)(mb + i) * N + n] = f2b(v);
            }
        }
    }
}

// ---------------- dvec[r] = t[r,:256] . d2_w + d2_b
__global__ __launch_bounds__(256) void k_dvec(const float* __restrict__ tmat, const float* __restrict__ d2w,
                                              const float* __restrict__ d2b, float* __restrict__ dvec) {
    const int r = blockIdx.x * 4 + (threadIdx.x >> 6);
    const int lane = threadIdx.x & 63;
    const float* row = tmat + (size_t)r * 256;
    float acc = 0.f;
    for (int f = lane; f < 256; f += 64) acc += row[f] * d2w[f];
    for (int off = 32; off; off >>= 1) acc += __shfl_xor(acc, off);
    if (lane == 0) dvec[r] = acc + d2b[0];
}

// ---------------- channel decoder + abs
__global__ __launch_bounds__(64) void k_final(const float* __restrict__ dvec, const float* __restrict__ c1w,
                                              const float* __restrict__ c1b, const float* __restrict__ c2w,
                                              const float* __restrict__ c2b, float* __restrict__ out) {
    const int b = blockIdx.x;
    const int f = threadIdx.x;
    float part = 0.f;
    if (f < 32) {
        float acc = c1b[f];
        const float* dr = dvec + b * 64;
        for (int c = 0; c < 64; ++c) acc += dr[c] * c1w[f * 64 + c];
        acc = acc > 0.f ? acc : 0.f;
        part = acc * c2w[f];
    }
    for (int off = 32; off; off >>= 1) part += __shfl_xor(part, off);
    if (f == 0) out[b] = fabsf(part + c2b[0]);
}

extern "C" void kernel_launch(void* const* d_in, const int* in_sizes, int n_in,
                              void* d_out, int out_size, void* d_ws, size_t ws_size,
                              hipStream_t stream) {
    const float* x     = (const float*)d_in[0];
    const float* occ   = (const float*)d_in[1];
    const float* projw = (const float*)d_in[2];
    const float* projb = (const float*)d_in[3];
    const float* ll1w  = (const float*)d_in[4];
    const float* ll1b  = (const float*)d_in[5];
    const float* ll2w  = (const float*)d_in[6];
    const float* ll2b  = (const float*)d_in[7];
    const float* g1w   = (const float*)d_in[8];
    const float* g1b   = (const float*)d_in[9];
    const float* g2w   = (const float*)d_in[10];
    const float* g2b   = (const float*)d_in[11];
    const float* gcw   = (const float*)d_in[12];
    const float* gcb   = (const float*)d_in[13];
    const float* taw   = (const float*)d_in[14];
    const float* tab   = (const float*)d_in[15];
    const float* d1w   = (const float*)d_in[16];
    const float* d1b   = (const float*)d_in[17];
    const float* d2w   = (const float*)d_in[18];
    const float* d2b   = (const float*)d_in[19];
    const float* c1w   = (const float*)d_in[20];
    const float* c1b   = (const float*)d_in[21];
    const float* c2w   = (const float*)d_in[22];
    const float* c2b   = (const float*)d_in[23];

    const size_t MR = (size_t)16384 * 512;
    float* ws   = (float*)d_ws;
    float* xmA  = ws;                         // fp32 state A
    float* xmB  = xmA + MR;                   // fp32 state B
    float* x2T  = xmB + MR;                   // d1 output (fp32)
    float* vbuf = x2T + MR;                   // 16384*128
    float* proj = vbuf + (size_t)16384 * 128;
    float* m1m2 = proj + 16384;               // (unused slot, kept for layout stability)
    float* dvec = m1m2 + 32768;
    u16* bfb     = (u16*)(dvec + 16384);
    u16* xmA_bf  = bfb;
    u16* xmB_bf  = xmA_bf + MR;
    u16* x1_bf   = xmB_bf + MR;
    u16* x2_bf   = x1_bf + MR;
    u16* x1T_bf  = x2_bf + MR;                // ta output (bf16 only)
    u16* adpT_bf = x1T_bf + MR;               // 16384*64
    u16* ll1w_bf = adpT_bf + (size_t)16384 * 64;
    u16* ll2w_bf = ll1w_bf + 98304;
    u16* gcw_bf  = ll2w_bf + 98304;           // 3*512*1536
    u16* taw_bf  = gcw_bf + 2359296;
    u16* d1w_bf  = taw_bf + 262144;

    k_cvt<<<96,   256, 0, stream>>>(ll1w, ll1w_bf, 98304 / 4);
    k_cvt<<<96,   256, 0, stream>>>(ll2w, ll2w_bf, 98304 / 4);
    k_cvt<<<2304, 256, 0, stream>>>(gcw,  gcw_bf,  2359296 / 4);
    k_cvt<<<256,  256, 0, stream>>>(taw,  taw_bf,  262144 / 4);
    k_cvt<<<128,  256, 0, stream>>>(d1w,  d1w_bf,  131072 / 4);

    k_transpose<<<dim3(8, 256), 256, 0, stream>>>(x, xmA, xmA_bf);
    k_proj<<<256, 64, 0, stream>>>(occ, projw, projb, proj);

    float* cur = xmA;  u16* cur_bf = xmA_bf;
    float* nxt = xmB;  u16* nxt_bf = xmB_bf;
    for (int l = 0; l < 3; ++l) {
        mfma_gemm<64, 64><<<dim3(256, 2), 256, 0, stream>>>(
            cur_bf, nullptr, nullptr,
            ll1w_bf + (size_t)l * 32768, ll2w_bf + (size_t)l * 32768, 64,
            ll1b + l * 64, ll2b + l * 64, nullptr, vbuf, nullptr, 128, 512, 0);
        k_pm<<<16384, 64, 0, stream>>>(cur_bf, g1w + l * 576, g1b + l, g2w + l * 576, g2b + l, proj, vbuf);
        k_adp<<<256, 256, 0, stream>>>(vbuf, adpT_bf);
        k_nconv2<<<dim3(4, 256), 256, 0, stream>>>(cur_bf, adpT_bf, x1_bf, x2_bf);
        mfma_gemm<128, 64><<<dim3(128, 8), 256, 0, stream>>>(
            cur_bf, x1_bf, x2_bf,
            gcw_bf + (size_t)l * 786432, gcw_bf + (size_t)l * 786432, 512,
            gcb + l * 512, gcb + l * 512, (l > 0 ? cur : nullptr), nxt, nxt_bf, 512, 1536, 1);
        { float* tf = cur; cur = nxt; nxt = tf; }
        { u16* tb = cur_bf; cur_bf = nxt_bf; nxt_bf = tb; }
    }
    // temporal_agg: bf16-only output
    mfma_gemm<128, 64><<<dim3(128, 8), 256, 0, stream>>>(
        cur_bf, nullptr, nullptr, taw_bf, taw_bf, 512, tab, tab, nullptr, nullptr, x1T_bf, 512, 512, 0);
    // decoder1: fp32 output
    mfma_gemm<64, 64><<<dim3(256, 4), 256, 0, stream>>>(
        x1T_bf, nullptr, nullptr, d1w_bf, d1w_bf, 256, d1b, d1b, nullptr, x2T, nullptr, 256, 512, 1);
    k_dvec<<<4096, 256, 0, stream>>>(x2T, d2w, d2b, dvec);
    k_final<<<256, 64, 0, stream>>>(dvec, c1w, c1b, c2w, c2b, (float*)d_out);
}